// Round 9
// baseline (1362.646 us; speedup 1.0000x reference)
//
#include <hip/hip_runtime.h>
#include <hip/hip_bf16.h>
#include <stdint.h>

// PointNet++ Set Abstraction: FPS -> ball query -> gather -> 3x(conv1x1+BN+ReLU) -> maxpool
// B=8 N=8192 C=64, npoint=1024, r=0.2, nsample=32, MLP 67->64->64->128, BN_EPS=1e-3
//
// Exactness notes:
//  * FPS / ball query distances: exact per-op IEEE f32, order ((dx*dx+dy*dy)+dz*dz).
//    fps uses ext_vector <2 x float> ops under "#pragma clang fp contract(off)";
//    ballquery keeps _rn intrinsics.
//  * FPS argmax tie-break = first (lowest) global index: per-thread lowest slot with
//    dist==bestv via cmp+min-tree (latency ~25cyc, overlaps DPP chain); exact wave
//    value-max (DPP) -> readlane wm; threads with bestv!=wm invalidated (idx=~0);
//    wave min-idx (DPP); cross-wave u64 key (distbits<<32)|~idx maximized. Winner
//    identical to reference first-index argmax.
//  * Ball query keeps first 32 valid indices in ascending order, pads with first hit.
//  * MLP layers run on MFMA (bf16 in, f32 accum). BN stats from f32 accumulators.
//  * max-over-k commutes with relu(bn(.)) (bn slope > 0) -> layer2 stores only the
//    per-(b,s) channel max of z2.

#define INV_CNT (1.0f/262144.0f)

typedef __attribute__((ext_vector_type(8))) short bf16x8;
typedef __attribute__((ext_vector_type(4))) float f32x4;
typedef __attribute__((ext_vector_type(2))) float f32x2;

__device__ __forceinline__ float bf2f(unsigned int v) {
    return __uint_as_float(v << 16);
}
__device__ __forceinline__ unsigned int f2bf(float f) {
    unsigned int u = __float_as_uint(f);
    return (u + 0x7fffu + ((u >> 16) & 1u)) >> 16;   // RNE
}

template<int CTRL>
__device__ __forceinline__ unsigned int dpp_u32(unsigned int x) {
    return (unsigned int)__builtin_amdgcn_update_dpp((int)x, (int)x, CTRL, 0xf, 0xf, false);
}
template<int CTRL>
__device__ __forceinline__ float dpp_f32(float x) {
    return __uint_as_float(dpp_u32<CTRL>(__float_as_uint(x)));
}
// DPP ctrl: ROW_SHR:n = 0x110|n, ROW_BCAST15 = 0x142, ROW_BCAST31 = 0x143

// ---------------- FPS: one block per batch, 256 threads, 32 pts/thread ----------------
__global__ __launch_bounds__(256) void fps_kernel(const float* __restrict__ xyz,
                                                  float* __restrict__ nxyz,
                                                  float* __restrict__ out_nxyz) {
#pragma clang fp contract(off)
    const int b = blockIdx.x;
    const int t = threadIdx.x;                               // 0..255
    const int lane = t & 63;
    const int wv = t >> 6;                                   // 0..3
    const float* xb = xyz + (size_t)b * 8192 * 3;
    __shared__ float4 sxyz[8192];                            // 128 KB coord mirror
    __shared__ unsigned long long sdk[2][4];                 // per-wave (distbits<<32)|~idx
    __shared__ int ch[1024];
    f32x2 px[16], py[16], pz[16], dist[16];                  // pair j: pts t+2j*256, t+(2j+1)*256
#pragma unroll
    for (int j = 0; j < 16; ++j) {
        int p0 = t + (2*j)*256, p1 = t + (2*j+1)*256;
        float x0 = xb[p0*3+0], y0 = xb[p0*3+1], z0 = xb[p0*3+2];
        float x1 = xb[p1*3+0], y1 = xb[p1*3+1], z1 = xb[p1*3+2];
        px[j] = (f32x2){x0, x1}; py[j] = (f32x2){y0, y1}; pz[j] = (f32x2){z0, z1};
        sxyz[p0] = make_float4(x0, y0, z0, 0.f);
        sxyz[p1] = make_float4(x1, y1, z1, 0.f);
        dist[j] = (f32x2){1e10f, 1e10f};
    }
    __syncthreads();
    int far = 0;
    for (int it = 0; it < 1024; ++it) {
        if (t == 0) ch[it] = far;
        float4 c4 = sxyz[far];                               // one ds_read_b128, broadcast
        f32x2 c2x = (f32x2){c4.x, c4.x}, c2y = (f32x2){c4.y, c4.y}, c2z = (f32x2){c4.z, c4.z};
        float bv0 = -1.f, bv1 = -1.f;
#pragma unroll
        for (int j = 0; j < 16; ++j) {
            f32x2 dx = px[j] - c2x;                          // <2 x float>: v_pk_* eligible
            f32x2 dy = py[j] - c2y;
            f32x2 dz = pz[j] - c2z;
            f32x2 dd = (dx*dx + dy*dy) + dz*dz;              // contract(off): exact per-op
            float n0 = fminf(dist[j][0], dd[0]);
            float n1 = fminf(dist[j][1], dd[1]);
            dist[j][0] = n0; dist[j][1] = n1;
            bv0 = fmaxf(bv0, n0); bv1 = fmaxf(bv1, n1);
        }
        float bestv = fmaxf(bv0, bv1);
        // local lowest slot with dist == bestv, via cmp + 5-deep min-tree (~25cyc latency,
        // independent of the DPP value chain -> overlaps it in the in-order issue stream)
        unsigned int cand[32];
#pragma unroll
        for (int j = 0; j < 16; ++j) {
            cand[2*j]   = (dist[j][0] == bestv) ? (unsigned int)(2*j)   : 64u;
            cand[2*j+1] = (dist[j][1] == bestv) ? (unsigned int)(2*j+1) : 64u;
        }
#pragma unroll
        for (int s = 16; s >= 1; s >>= 1)
#pragma unroll
            for (int i = 0; i < s; ++i) cand[i] = (cand[i+s] < cand[i]) ? cand[i+s] : cand[i];
        // wave64 exact value max via DPP (accumulates into lane 63)
        float v = bestv;
        v = fmaxf(v, dpp_f32<0x111>(v));
        v = fmaxf(v, dpp_f32<0x112>(v));
        v = fmaxf(v, dpp_f32<0x114>(v));
        v = fmaxf(v, dpp_f32<0x118>(v));
        v = fmaxf(v, dpp_f32<0x142>(v));
        v = fmaxf(v, dpp_f32<0x143>(v));
        unsigned int wmu = (unsigned int)__builtin_amdgcn_readlane((int)__float_as_uint(v), 63);
        float wm = __uint_as_float(wmu);
        unsigned int idx = (unsigned int)t + (cand[0] << 8); // global candidate index
        if (bestv != wm) idx = 0xffffffffu;                  // losers never win the min
        // wave min of idx via DPP (accumulates into lane 63)
        { unsigned int n;
          n = dpp_u32<0x111>(idx); idx = (n < idx) ? n : idx;
          n = dpp_u32<0x112>(idx); idx = (n < idx) ? n : idx;
          n = dpp_u32<0x114>(idx); idx = (n < idx) ? n : idx;
          n = dpp_u32<0x118>(idx); idx = (n < idx) ? n : idx;
          n = dpp_u32<0x142>(idx); idx = (n < idx) ? n : idx;
          n = dpp_u32<0x143>(idx); idx = (n < idx) ? n : idx; }
        if (lane == 63)
            sdk[it & 1][wv] = ((unsigned long long)wmu << 32) | (unsigned long long)(~idx);
        __syncthreads();                                     // the only barrier per iter
        unsigned long long k = sdk[it & 1][lane & 3];
        unsigned int xh = (unsigned int)(k >> 32), xl = (unsigned int)k;
        // 2-step DPP u64-key max over 4 wave partials (result lands in lane 3)
#define XSTEP(C) { unsigned int nh = dpp_u32<C>(xh), nl = dpp_u32<C>(xl);          \
                   unsigned long long nk = ((unsigned long long)nh << 32) | nl;     \
                   unsigned long long ck = ((unsigned long long)xh << 32) | xl;     \
                   bool tk = nk > ck; xh = tk ? nh : xh; xl = tk ? nl : xl; }
        XSTEP(0x111) XSTEP(0x112)
#undef XSTEP
        far = (int)(~(unsigned int)__builtin_amdgcn_readlane((int)xl, 3)) & 8191;
    }
    __syncthreads();
    for (int j = t; j < 1024; j += 256) {
        float4 c4 = sxyz[ch[j]];
        size_t o = (size_t)(b*1024 + j) * 3;
        nxyz[o] = c4.x; nxyz[o+1] = c4.y; nxyz[o+2] = c4.z;
        out_nxyz[o] = c4.x; out_nxyz[o+1] = c4.y; out_nxyz[o+2] = c4.z;
    }
}

// ---------------- Ball query: one wave per center ----------------
__global__ __launch_bounds__(256) void ballquery_kernel(const float* __restrict__ xyz,
                                                        const float* __restrict__ nxyz,
                                                        int* __restrict__ idxbuf) {
    const int wib = threadIdx.x >> 6;
    const int lane = threadIdx.x & 63;
    const int c = blockIdx.x * 4 + wib;        // center id in [0, 8192)
    const int b = c >> 10;
    const float* xb = xyz + (size_t)b * 8192 * 3;
    const float cx = nxyz[c*3+0], cy = nxyz[c*3+1], cz = nxyz[c*3+2];
    const float R2 = 0.04f;
    int count = 0, first = 0;
    int* ob = idxbuf + (size_t)c * 32;
    for (int base = 0; base < 8192; base += 64) {
        int i = base + lane;
        float dx = __fsub_rn(xb[i*3+0], cx);
        float dy = __fsub_rn(xb[i*3+1], cy);
        float dz = __fsub_rn(xb[i*3+2], cz);
        float sq = __fadd_rn(__fadd_rn(__fmul_rn(dx,dx), __fmul_rn(dy,dy)), __fmul_rn(dz,dz));
        bool pass = !(sq > R2);
        unsigned long long mask = __ballot(pass);
        if (count == 0 && mask) first = base + (int)__builtin_ctzll(mask);
        int pos = count + (int)__popcll(mask & ((1ull << lane) - 1ull));
        if (pass && pos < 32) ob[pos] = i;
        count += (int)__popcll(mask);
        if (count >= 32) break;
    }
    if (count < 32 && lane >= count && lane < 32) ob[lane] = first;
}

// ---------------- Weight prep: bf16, transposed, padded (run once per launch) ----------------
__global__ __launch_bounds__(256) void prep_w(const float* __restrict__ w0,
                                              const float* __restrict__ w1,
                                              const float* __restrict__ w2,
                                              unsigned short* __restrict__ wt0,
                                              unsigned short* __restrict__ wt1,
                                              unsigned short* __restrict__ wt2) {
    const int i0 = blockIdx.x * 256 + threadIdx.x;
    const int stride = gridDim.x * 256;
    for (int i = i0; i < 64*104; i += stride) {
        int f = i / 104, k = i - f*104;
        wt0[i] = (k < 67) ? (unsigned short)f2bf(w0[k*64 + f]) : (unsigned short)0;
    }
    for (int i = i0; i < 64*72; i += stride) {
        int f = i / 72, k = i - f*72;
        wt1[i] = (k < 64) ? (unsigned short)f2bf(w1[k*64 + f]) : (unsigned short)0;
    }
    for (int i = i0; i < 128*72; i += stride) {
        int f = i / 72, k = i - f*72;
        wt2[i] = (k < 64) ? (unsigned short)f2bf(w2[k*128 + f]) : (unsigned short)0;
    }
}

// ======================= MFMA MLP layers =======================
// Tile: 64 rows x F per block, 4 waves, wave w owns rows [16w,16w+16).
// A-frag: lane l -> row (l&15), k = 8*(l>>4)+[0..7]  (ds_read_b128 from Xb)
// B-frag: lane l -> col (l&15), same k pattern        (ds_read_b128 from Wt, transposed)
// C/D   : lane l -> col (l&15), rows 4*(l>>4)+reg     (HW-verified mapping)

// ---------------- Layer 0: gather(67) @ w0(67x64), K padded to 96, stride 104 ----------------
__global__ __launch_bounds__(256) void layer0_kernel(
        const float* __restrict__ xyz, const float* __restrict__ points,
        const float* __restrict__ nxyz, const int* __restrict__ idxbuf,
        const unsigned short* __restrict__ wt0, unsigned short* __restrict__ z0,
        float* __restrict__ stats0) {
    __shared__ __attribute__((aligned(16))) unsigned short Xb[64*104];
    __shared__ __attribute__((aligned(16))) unsigned short Wt[64*104];
    __shared__ float ssum[64], ssq[64];
    const int tid = threadIdx.x;
    const int R = blockIdx.x * 64;
    if (tid < 64) { ssum[tid] = 0.f; ssq[tid] = 0.f; }
    // W copy: pre-transposed bf16, vectorized
    {
        const uint4* src = (const uint4*)wt0;
        uint4* dst = (uint4*)Wt;
        for (int i = tid; i < 64*104/8; i += 256) dst[i] = src[i];
    }
    // X gather: 4 threads per row, float4 vector loads of points
    {
        int r = tid >> 2, q = tid & 3;
        int row = R + r;
        int gi = idxbuf[row];
        int b = row >> 15, s = (row >> 5) & 1023;
        const float4* pb4 = (const float4*)(points + (size_t)(b*8192 + gi) * 64);
        float4 f0 = pb4[q*4+0], f1 = pb4[q*4+1], f2 = pb4[q*4+2], f3 = pb4[q*4+3];
        unsigned short* xr = &Xb[r*104 + 3 + q*16];
        xr[0]  = (unsigned short)f2bf(f0.x); xr[1]  = (unsigned short)f2bf(f0.y);
        xr[2]  = (unsigned short)f2bf(f0.z); xr[3]  = (unsigned short)f2bf(f0.w);
        xr[4]  = (unsigned short)f2bf(f1.x); xr[5]  = (unsigned short)f2bf(f1.y);
        xr[6]  = (unsigned short)f2bf(f1.z); xr[7]  = (unsigned short)f2bf(f1.w);
        xr[8]  = (unsigned short)f2bf(f2.x); xr[9]  = (unsigned short)f2bf(f2.y);
        xr[10] = (unsigned short)f2bf(f2.z); xr[11] = (unsigned short)f2bf(f2.w);
        xr[12] = (unsigned short)f2bf(f3.x); xr[13] = (unsigned short)f2bf(f3.y);
        xr[14] = (unsigned short)f2bf(f3.z); xr[15] = (unsigned short)f2bf(f3.w);
        if (q == 0) {
#pragma unroll
            for (int e = 0; e < 3; ++e) {
                float vv = xyz[(size_t)(b*8192+gi)*3 + e] - nxyz[(size_t)(b*1024+s)*3 + e];
                Xb[r*104 + e] = (unsigned short)f2bf(vv);
            }
        }
    }
    // zero-pad k in [67,96)
    for (int i = tid; i < 29*64; i += 256) {
        int e = 67 + (i % 29), r = i / 29;
        Xb[r*104 + e] = 0;
    }
    __syncthreads();
    const int l = tid & 63, w = tid >> 6;
    const int rsub = l & 15, kq = l >> 4;
    f32x4 acc[4];
#pragma unroll
    for (int cb = 0; cb < 4; ++cb) acc[cb] = (f32x4){0.f, 0.f, 0.f, 0.f};
    const int abase = (w*16 + rsub)*104 + kq*8;
    const int bbase = rsub*104 + kq*8;
#pragma unroll
    for (int ks = 0; ks < 3; ++ks) {
        bf16x8 A = *(const bf16x8*)&Xb[abase + ks*32];
#pragma unroll
        for (int cb = 0; cb < 4; ++cb) {
            bf16x8 Bf = *(const bf16x8*)&Wt[bbase + cb*16*104 + ks*32];
            acc[cb] = __builtin_amdgcn_mfma_f32_16x16x32_bf16(A, Bf, acc[cb], 0, 0, 0);
        }
    }
    unsigned short* zrow = z0 + (size_t)(R + w*16 + kq*4) * 64;
#pragma unroll
    for (int cb = 0; cb < 4; ++cb) {
        int c = cb*16 + rsub;
        float a0 = acc[cb][0], a1 = acc[cb][1], a2 = acc[cb][2], a3 = acc[cb][3];
        atomicAdd(&ssum[c], a0 + a1 + a2 + a3);
        atomicAdd(&ssq[c], a0*a0 + a1*a1 + a2*a2 + a3*a3);
#pragma unroll
        for (int j = 0; j < 4; ++j) zrow[j*64 + c] = (unsigned short)f2bf(acc[cb][j]);
    }
    __syncthreads();
    if (tid < 64) {
        atomicAdd(&stats0[tid], ssum[tid]);
        atomicAdd(&stats0[64+tid], ssq[tid]);
    }
}

// ---------------- Layer 1: relu(bn0(z0)) @ w1(64x64), stride 72 ----------------
__global__ __launch_bounds__(256) void layer1_kernel(
        const unsigned short* __restrict__ z0, const float* __restrict__ stats0,
        const float* __restrict__ gamma0, const float* __restrict__ beta0,
        const unsigned short* __restrict__ wt1, unsigned short* __restrict__ z1,
        float* __restrict__ stats1) {
    __shared__ __attribute__((aligned(16))) unsigned short Xb[64*72];
    __shared__ __attribute__((aligned(16))) unsigned short Wt[64*72];
    __shared__ float scale[64], shift[64], ssum[64], ssq[64];
    const int tid = threadIdx.x;
    const int R = blockIdx.x * 64;
    if (tid < 64) {
        float m = stats0[tid] * INV_CNT;
        float v = stats0[64+tid] * INV_CNT - m*m;
        float rs = rsqrtf(v + 1e-3f);
        float sc = gamma0[tid] * rs;
        scale[tid] = sc; shift[tid] = beta0[tid] - m*sc;
        ssum[tid] = 0.f; ssq[tid] = 0.f;
    }
    {
        const uint4* src = (const uint4*)wt1;
        uint4* dst = (uint4*)Wt;
        for (int i = tid; i < 64*72/8; i += 256) dst[i] = src[i];
    }
    __syncthreads();                           // scale/shift ready
    const uint4* zg = (const uint4*)(z0 + (size_t)R * 64);
#pragma unroll
    for (int cch = 0; cch < 2; ++cch) {
        int flat8 = tid*2 + cch;               // 8-elem chunk id, 0..511
        uint4 a = zg[flat8];
        int r = flat8 >> 3, e0 = (flat8 & 7) * 8;
        unsigned int uu[4] = {a.x, a.y, a.z, a.w};
        bf16x8 xv;
#pragma unroll
        for (int j = 0; j < 8; ++j) {
            unsigned int ub = (j & 1) ? (uu[j>>1] >> 16) : (uu[j>>1] & 0xffffu);
            float v = bf2f(ub);
            v = fmaxf(v * scale[e0+j] + shift[e0+j], 0.f);
            xv[j] = (short)f2bf(v);
        }
        *(bf16x8*)&Xb[r*72 + e0] = xv;
    }
    __syncthreads();
    const int l = tid & 63, w = tid >> 6;
    const int rsub = l & 15, kq = l >> 4;
    f32x4 acc[4];
#pragma unroll
    for (int cb = 0; cb < 4; ++cb) acc[cb] = (f32x4){0.f, 0.f, 0.f, 0.f};
    const int abase = (w*16 + rsub)*72 + kq*8;
    const int bbase = rsub*72 + kq*8;
#pragma unroll
    for (int ks = 0; ks < 2; ++ks) {
        bf16x8 A = *(const bf16x8*)&Xb[abase + ks*32];
#pragma unroll
        for (int cb = 0; cb < 4; ++cb) {
            bf16x8 Bf = *(const bf16x8*)&Wt[bbase + cb*16*72 + ks*32];
            acc[cb] = __builtin_amdgcn_mfma_f32_16x16x32_bf16(A, Bf, acc[cb], 0, 0, 0);
        }
    }
    unsigned short* zrow = z1 + (size_t)(R + w*16 + kq*4) * 64;
#pragma unroll
    for (int cb = 0; cb < 4; ++cb) {
        int c = cb*16 + rsub;
        float a0 = acc[cb][0], a1 = acc[cb][1], a2 = acc[cb][2], a3 = acc[cb][3];
        atomicAdd(&ssum[c], a0 + a1 + a2 + a3);
        atomicAdd(&ssq[c], a0*a0 + a1*a1 + a2*a2 + a3*a3);
#pragma unroll
        for (int j = 0; j < 4; ++j) zrow[j*64 + c] = (unsigned short)f2bf(acc[cb][j]);
    }
    __syncthreads();
    if (tid < 64) {
        atomicAdd(&stats1[tid], ssum[tid]);
        atomicAdd(&stats1[64+tid], ssq[tid]);
    }
}

// ------- Layer 2: relu(bn1(z1)) @ w2(64x128); per-(b,s) channel max + stats -------
__global__ __launch_bounds__(256) void layer2_kernel(
        const unsigned short* __restrict__ z1, const float* __restrict__ stats1,
        const float* __restrict__ gamma1, const float* __restrict__ beta1,
        const unsigned short* __restrict__ wt2, float* __restrict__ maxz2,
        float* __restrict__ stats2) {
    __shared__ __attribute__((aligned(16))) unsigned short Xb[64*72];
    __shared__ __attribute__((aligned(16))) unsigned short Wt[128*72];
    __shared__ float scale[64], shift[64];
    __shared__ float ssum[128], ssq[128];
    __shared__ float gmx[2][8][128];
    const int tid = threadIdx.x;
    const int R = blockIdx.x * 64;
    if (tid < 64) {
        float m = stats1[tid] * INV_CNT;
        float v = stats1[64+tid] * INV_CNT - m*m;
        float rs = rsqrtf(v + 1e-3f);
        float sc = gamma1[tid] * rs;
        scale[tid] = sc; shift[tid] = beta1[tid] - m*sc;
    }
    if (tid < 128) { ssum[tid] = 0.f; ssq[tid] = 0.f; }
    {
        const uint4* src = (const uint4*)wt2;
        uint4* dst = (uint4*)Wt;
        for (int i = tid; i < 128*72/8; i += 256) dst[i] = src[i];
    }
    __syncthreads();
    const uint4* zg = (const uint4*)(z1 + (size_t)R * 64);
#pragma unroll
    for (int cch = 0; cch < 2; ++cch) {
        int flat8 = tid*2 + cch;
        uint4 a = zg[flat8];
        int r = flat8 >> 3, e0 = (flat8 & 7) * 8;
        unsigned int uu[4] = {a.x, a.y, a.z, a.w};
        bf16x8 xv;
#pragma unroll
        for (int j = 0; j < 8; ++j) {
            unsigned int ub = (j & 1) ? (uu[j>>1] >> 16) : (uu[j>>1] & 0xffffu);
            float v = bf2f(ub);
            v = fmaxf(v * scale[e0+j] + shift[e0+j], 0.f);
            xv[j] = (short)f2bf(v);
        }
        *(bf16x8*)&Xb[r*72 + e0] = xv;
    }
    __syncthreads();
    const int l = tid & 63, w = tid >> 6;
    const int rsub = l & 15, kq = l >> 4;
    f32x4 acc[8];
#pragma unroll
    for (int cb = 0; cb < 8; ++cb) acc[cb] = (f32x4){0.f, 0.f, 0.f, 0.f};
    const int abase = (w*16 + rsub)*72 + kq*8;
    const int bbase = rsub*72 + kq*8;
#pragma unroll
    for (int ks = 0; ks < 2; ++ks) {
        bf16x8 A = *(const bf16x8*)&Xb[abase + ks*32];
#pragma unroll
        for (int cb = 0; cb < 8; ++cb) {
            bf16x8 Bf = *(const bf16x8*)&Wt[bbase + cb*16*72 + ks*32];
            acc[cb] = __builtin_amdgcn_mfma_f32_16x16x32_bf16(A, Bf, acc[cb], 0, 0, 0);
        }
    }
    const int g = w >> 1;                       // 32-row group within block
    const int contrib = (w & 1) * 4 + kq;       // 0..7
#pragma unroll
    for (int cb = 0; cb < 8; ++cb) {
        int c = cb*16 + rsub;
        float a0 = acc[cb][0], a1 = acc[cb][1], a2 = acc[cb][2], a3 = acc[cb][3];
        atomicAdd(&ssum[c], a0 + a1 + a2 + a3);
        atomicAdd(&ssq[c], a0*a0 + a1*a1 + a2*a2 + a3*a3);
        gmx[g][contrib][c] = fmaxf(fmaxf(a0, a1), fmaxf(a2, a3));
    }
    __syncthreads();
    {
        int gg = tid >> 7, c = tid & 127;
        float m = gmx[gg][0][c];
#pragma unroll
        for (int i = 1; i < 8; ++i) m = fmaxf(m, gmx[gg][i][c]);
        maxz2[(size_t)(blockIdx.x*2 + gg) * 128 + c] = m;
    }
    if (tid < 128) {
        atomicAdd(&stats2[tid], ssum[tid]);
        atomicAdd(&stats2[128+tid], ssq[tid]);
    }
}

// ---------------- Final: out = relu(bn2(maxz2)) ----------------
__global__ __launch_bounds__(256) void final_kernel(
        const float* __restrict__ maxz2, const float* __restrict__ stats2,
        const float* __restrict__ gamma2, const float* __restrict__ beta2,
        float* __restrict__ out) {
    const int i = blockIdx.x * 256 + threadIdx.x;    // over 8*1024*128
    const int f = i & 127;
    float m = stats2[f] * INV_CNT;
    float v = stats2[128+f] * INV_CNT - m*m;
    float rs = rsqrtf(v + 1e-3f);
    out[24576 + i] = fmaxf(gamma2[f]*((maxz2[i]-m)*rs) + beta2[f], 0.f);
}

extern "C" void kernel_launch(void* const* d_in, const int* in_sizes, int n_in,
                              void* d_out, int out_size, void* d_ws, size_t ws_size,
                              hipStream_t stream) {
    const float* xyz    = (const float*)d_in[0];
    const float* points = (const float*)d_in[1];
    const float* w0     = (const float*)d_in[2];
    const float* g0     = (const float*)d_in[3];
    const float* b0     = (const float*)d_in[4];
    const float* w1     = (const float*)d_in[5];
    const float* g1     = (const float*)d_in[6];
    const float* b1     = (const float*)d_in[7];
    const float* w2     = (const float*)d_in[8];
    const float* g2     = (const float*)d_in[9];
    const float* b2     = (const float*)d_in[10];
    float* out = (float*)d_out;
    char* ws = (char*)d_ws;

    // workspace layout (bytes), all 256-aligned:
    float* nxyz            = (float*)(ws + 0);          // 24576 f32
    int*   idxbuf          = (int*)  (ws + 98304);      // 262144 i32
    float* stats           = (float*)(ws + 1146880);    // 512 f32 (s0:128, s1:128, s2:256)
    unsigned short* z0     = (unsigned short*)(ws + 1148928);   // 32 MB bf16
    unsigned short* z1     = (unsigned short*)(ws + 34703360);  // 32 MB bf16
    float* maxz2           = (float*)(ws + 68257792);   // 4 MB f32
    unsigned short* wt0    = (unsigned short*)(ws + 72452096);  // 64*104 bf16
    unsigned short* wt1    = (unsigned short*)(ws + 72465408);  // 64*72 bf16
    unsigned short* wt2    = (unsigned short*)(ws + 72474624);  // 128*72 bf16

    hipMemsetAsync(stats, 0, 512 * sizeof(float), stream);
    prep_w<<<26, 256, 0, stream>>>(w0, w1, w2, wt0, wt1, wt2);
    fps_kernel<<<8, 256, 0, stream>>>(xyz, nxyz, out);
    ballquery_kernel<<<2048, 256, 0, stream>>>(xyz, nxyz, idxbuf);
    layer0_kernel<<<4096, 256, 0, stream>>>(xyz, points, nxyz, idxbuf, wt0, z0, stats);
    layer1_kernel<<<4096, 256, 0, stream>>>(z0, stats, g0, b0, wt1, z1, stats + 128);
    layer2_kernel<<<4096, 256, 0, stream>>>(z1, stats + 128, g1, b1, wt2, maxz2, stats + 256);
    final_kernel<<<4096, 256, 0, stream>>>(maxz2, stats + 256, g2, b2, out);
}

// Round 10
// 1249.072 us; speedup vs baseline: 1.0909x; 1.0909x over previous
//
#include <hip/hip_runtime.h>
#include <hip/hip_bf16.h>
#include <stdint.h>

// PointNet++ Set Abstraction: FPS -> ball query -> gather -> 3x(conv1x1+BN+ReLU) -> maxpool
// B=8 N=8192 C=64, npoint=1024, r=0.2, nsample=32, MLP 67->64->64->128, BN_EPS=1e-3
//
// Exactness notes:
//  * FPS / ball query distances: exact per-op IEEE f32, order ((dx*dx+dy*dy)+dz*dz).
//    fps uses ext_vector <2 x float> ops under "#pragma clang fp contract(off)";
//    ballquery keeps _rn intrinsics.
//  * FPS argmax tie-break = first (lowest) global index: exact value max via
//    max3-fusable tree + DPP wave max; per-thread lowest slot with dist==bestv via
//    cmp+min-tree; losers invalidated after readlane; wave min-idx (DPP); cross-wave
//    u64 key (distbits<<32)|~idx maximized. Winner identical to reference argmax.
//  * Ball query keeps first 32 valid indices in ascending order, pads with first hit.
//  * MLP layers run on MFMA (bf16 in, f32 accum). BN stats accumulate via 32-way
//    BANKED global atomics (blockIdx&31) to kill same-line L2 atomic serialization;
//    tiny bnprep kernels fold banks and precompute scale/shift per channel.
//  * max-over-k commutes with relu(bn(.)) (bn slope > 0) -> layer2 stores only the
//    per-(b,s) channel max of z2.

#define INV_CNT (1.0f/262144.0f)

typedef __attribute__((ext_vector_type(8))) short bf16x8;
typedef __attribute__((ext_vector_type(4))) float f32x4;
typedef __attribute__((ext_vector_type(2))) float f32x2;

__device__ __forceinline__ float bf2f(unsigned int v) {
    return __uint_as_float(v << 16);
}
__device__ __forceinline__ unsigned int f2bf(float f) {
    unsigned int u = __float_as_uint(f);
    return (u + 0x7fffu + ((u >> 16) & 1u)) >> 16;   // RNE
}

template<int CTRL>
__device__ __forceinline__ unsigned int dpp_u32(unsigned int x) {
    return (unsigned int)__builtin_amdgcn_update_dpp((int)x, (int)x, CTRL, 0xf, 0xf, false);
}
template<int CTRL>
__device__ __forceinline__ float dpp_f32(float x) {
    return __uint_as_float(dpp_u32<CTRL>(__float_as_uint(x)));
}
// DPP ctrl: ROW_SHR:n = 0x110|n, ROW_BCAST15 = 0x142, ROW_BCAST31 = 0x143

// ---------------- FPS: one block per batch, 256 threads, 32 pts/thread ----------------
__global__ __launch_bounds__(256) void fps_kernel(const float* __restrict__ xyz,
                                                  float* __restrict__ nxyz,
                                                  float* __restrict__ out_nxyz) {
#pragma clang fp contract(off)
    const int b = blockIdx.x;
    const int t = threadIdx.x;                               // 0..255
    const int lane = t & 63;
    const int wv = t >> 6;                                   // 0..3
    const float* xb = xyz + (size_t)b * 8192 * 3;
    __shared__ float4 sxyz[8192];                            // 128 KB coord mirror
    __shared__ unsigned long long sdk[2][4];                 // per-wave (distbits<<32)|~idx
    __shared__ int ch[1024];
    f32x2 px[16], py[16], pz[16], dist[16];                  // pair j: pts t+2j*256, t+(2j+1)*256
#pragma unroll
    for (int j = 0; j < 16; ++j) {
        int p0 = t + (2*j)*256, p1 = t + (2*j+1)*256;
        float x0 = xb[p0*3+0], y0 = xb[p0*3+1], z0 = xb[p0*3+2];
        float x1 = xb[p1*3+0], y1 = xb[p1*3+1], z1 = xb[p1*3+2];
        px[j] = (f32x2){x0, x1}; py[j] = (f32x2){y0, y1}; pz[j] = (f32x2){z0, z1};
        sxyz[p0] = make_float4(x0, y0, z0, 0.f);
        sxyz[p1] = make_float4(x1, y1, z1, 0.f);
        dist[j] = (f32x2){1e10f, 1e10f};
    }
    __syncthreads();
    int far = 0;
    for (int it = 0; it < 1024; ++it) {
        if (t == 0) ch[it] = far;
        float4 c4 = sxyz[far];                               // one ds_read_b128, broadcast
        f32x2 c2x = (f32x2){c4.x, c4.x}, c2y = (f32x2){c4.y, c4.y}, c2z = (f32x2){c4.z, c4.z};
#pragma unroll
        for (int j = 0; j < 16; ++j) {
            f32x2 dx = px[j] - c2x;                          // <2 x float>: v_pk_* eligible
            f32x2 dy = py[j] - c2y;
            f32x2 dz = pz[j] - c2z;
            f32x2 dd = (dx*dx + dy*dy) + dz*dz;              // contract(off): exact per-op
            dist[j][0] = fminf(dist[j][0], dd[0]);
            dist[j][1] = fminf(dist[j][1], dd[1]);
        }
        // exact value max via max3-fusable tree (order-invariant for exact max)
        float tm[16];
#pragma unroll
        for (int j = 0; j < 16; ++j) tm[j] = fmaxf(dist[j][0], dist[j][1]);
        float g0 = fmaxf(fmaxf(tm[0], tm[1]), tm[2]);
        float g1 = fmaxf(fmaxf(tm[3], tm[4]), tm[5]);
        float g2 = fmaxf(fmaxf(tm[6], tm[7]), tm[8]);
        float g3 = fmaxf(fmaxf(tm[9], tm[10]), tm[11]);
        float g4 = fmaxf(fmaxf(tm[12], tm[13]), tm[14]);
        float h0 = fmaxf(fmaxf(g0, g1), g2);
        float h1 = fmaxf(fmaxf(g3, g4), tm[15]);
        float bestv = fmaxf(h0, h1);
        // local lowest slot with dist == bestv (cmp + min-tree, overlaps DPP chain)
        unsigned int cand[32];
#pragma unroll
        for (int j = 0; j < 16; ++j) {
            cand[2*j]   = (dist[j][0] == bestv) ? (unsigned int)(2*j)   : 64u;
            cand[2*j+1] = (dist[j][1] == bestv) ? (unsigned int)(2*j+1) : 64u;
        }
#pragma unroll
        for (int s = 16; s >= 1; s >>= 1)
#pragma unroll
            for (int i = 0; i < s; ++i) cand[i] = (cand[i+s] < cand[i]) ? cand[i+s] : cand[i];
        // wave64 exact value max via DPP (accumulates into lane 63)
        float v = bestv;
        v = fmaxf(v, dpp_f32<0x111>(v));
        v = fmaxf(v, dpp_f32<0x112>(v));
        v = fmaxf(v, dpp_f32<0x114>(v));
        v = fmaxf(v, dpp_f32<0x118>(v));
        v = fmaxf(v, dpp_f32<0x142>(v));
        v = fmaxf(v, dpp_f32<0x143>(v));
        unsigned int wmu = (unsigned int)__builtin_amdgcn_readlane((int)__float_as_uint(v), 63);
        float wm = __uint_as_float(wmu);
        unsigned int idx = (unsigned int)t + (cand[0] << 8); // global candidate index
        if (bestv != wm) idx = 0xffffffffu;                  // losers never win the min
        // wave min of idx via DPP (accumulates into lane 63)
        { unsigned int n;
          n = dpp_u32<0x111>(idx); idx = (n < idx) ? n : idx;
          n = dpp_u32<0x112>(idx); idx = (n < idx) ? n : idx;
          n = dpp_u32<0x114>(idx); idx = (n < idx) ? n : idx;
          n = dpp_u32<0x118>(idx); idx = (n < idx) ? n : idx;
          n = dpp_u32<0x142>(idx); idx = (n < idx) ? n : idx;
          n = dpp_u32<0x143>(idx); idx = (n < idx) ? n : idx; }
        if (lane == 63)
            sdk[it & 1][wv] = ((unsigned long long)wmu << 32) | (unsigned long long)(~idx);
        __syncthreads();                                     // the only barrier per iter
        unsigned long long k = sdk[it & 1][lane & 3];
        unsigned int xh = (unsigned int)(k >> 32), xl = (unsigned int)k;
        // 2-step DPP u64-key max over 4 wave partials (result lands in lane 3)
#define XSTEP(C) { unsigned int nh = dpp_u32<C>(xh), nl = dpp_u32<C>(xl);          \
                   unsigned long long nk = ((unsigned long long)nh << 32) | nl;     \
                   unsigned long long ck = ((unsigned long long)xh << 32) | xl;     \
                   bool tk = nk > ck; xh = tk ? nh : xh; xl = tk ? nl : xl; }
        XSTEP(0x111) XSTEP(0x112)
#undef XSTEP
        far = (int)(~(unsigned int)__builtin_amdgcn_readlane((int)xl, 3)) & 8191;
    }
    __syncthreads();
    for (int j = t; j < 1024; j += 256) {
        float4 c4 = sxyz[ch[j]];
        size_t o = (size_t)(b*1024 + j) * 3;
        nxyz[o] = c4.x; nxyz[o+1] = c4.y; nxyz[o+2] = c4.z;
        out_nxyz[o] = c4.x; out_nxyz[o+1] = c4.y; out_nxyz[o+2] = c4.z;
    }
}

// ---------------- Ball query: one wave per center ----------------
__global__ __launch_bounds__(256) void ballquery_kernel(const float* __restrict__ xyz,
                                                        const float* __restrict__ nxyz,
                                                        int* __restrict__ idxbuf) {
    const int wib = threadIdx.x >> 6;
    const int lane = threadIdx.x & 63;
    const int c = blockIdx.x * 4 + wib;        // center id in [0, 8192)
    const int b = c >> 10;
    const float* xb = xyz + (size_t)b * 8192 * 3;
    const float cx = nxyz[c*3+0], cy = nxyz[c*3+1], cz = nxyz[c*3+2];
    const float R2 = 0.04f;
    int count = 0, first = 0;
    int* ob = idxbuf + (size_t)c * 32;
    for (int base = 0; base < 8192; base += 64) {
        int i = base + lane;
        float dx = __fsub_rn(xb[i*3+0], cx);
        float dy = __fsub_rn(xb[i*3+1], cy);
        float dz = __fsub_rn(xb[i*3+2], cz);
        float sq = __fadd_rn(__fadd_rn(__fmul_rn(dx,dx), __fmul_rn(dy,dy)), __fmul_rn(dz,dz));
        bool pass = !(sq > R2);
        unsigned long long mask = __ballot(pass);
        if (count == 0 && mask) first = base + (int)__builtin_ctzll(mask);
        int pos = count + (int)__popcll(mask & ((1ull << lane) - 1ull));
        if (pass && pos < 32) ob[pos] = i;
        count += (int)__popcll(mask);
        if (count >= 32) break;
    }
    if (count < 32 && lane >= count && lane < 32) ob[lane] = first;
}

// ---------------- Weight prep: bf16, transposed, padded (run once per launch) ----------------
__global__ __launch_bounds__(256) void prep_w(const float* __restrict__ w0,
                                              const float* __restrict__ w1,
                                              const float* __restrict__ w2,
                                              unsigned short* __restrict__ wt0,
                                              unsigned short* __restrict__ wt1,
                                              unsigned short* __restrict__ wt2) {
    const int i0 = blockIdx.x * 256 + threadIdx.x;
    const int stride = gridDim.x * 256;
    for (int i = i0; i < 64*104; i += stride) {
        int f = i / 104, k = i - f*104;
        wt0[i] = (k < 67) ? (unsigned short)f2bf(w0[k*64 + f]) : (unsigned short)0;
    }
    for (int i = i0; i < 64*72; i += stride) {
        int f = i / 72, k = i - f*72;
        wt1[i] = (k < 64) ? (unsigned short)f2bf(w1[k*64 + f]) : (unsigned short)0;
    }
    for (int i = i0; i < 128*72; i += stride) {
        int f = i / 72, k = i - f*72;
        wt2[i] = (k < 64) ? (unsigned short)f2bf(w2[k*128 + f]) : (unsigned short)0;
    }
}

// ---------------- bnprep: fold 32 stat banks -> per-channel scale/shift ----------------
__global__ void bnprep64(const float* __restrict__ st,     // 32 banks x (64 sum + 64 sq)
                         const float* __restrict__ gamma, const float* __restrict__ beta,
                         float* __restrict__ sc, float* __restrict__ sh) {
    const int c = threadIdx.x;                              // 0..63
    float s = 0.f, q = 0.f;
    for (int b = 0; b < 32; ++b) { s += st[b*128 + c]; q += st[b*128 + 64 + c]; }
    float m = s * INV_CNT;
    float v = q * INV_CNT - m*m;
    float rs = rsqrtf(v + 1e-3f);
    float scl = gamma[c] * rs;
    sc[c] = scl; sh[c] = beta[c] - m*scl;
}
__global__ void bnprep128(const float* __restrict__ st,    // 32 banks x (128 sum + 128 sq)
                          const float* __restrict__ gamma, const float* __restrict__ beta,
                          float* __restrict__ sc, float* __restrict__ sh) {
    const int c = threadIdx.x;                              // 0..127
    float s = 0.f, q = 0.f;
    for (int b = 0; b < 32; ++b) { s += st[b*256 + c]; q += st[b*256 + 128 + c]; }
    float m = s * INV_CNT;
    float v = q * INV_CNT - m*m;
    float rs = rsqrtf(v + 1e-3f);
    float scl = gamma[c] * rs;
    sc[c] = scl; sh[c] = beta[c] - m*scl;
}

// ======================= MFMA MLP layers =======================
// Tile: 64 rows x F per block, 4 waves, wave w owns rows [16w,16w+16).
// A-frag: lane l -> row (l&15), k = 8*(l>>4)+[0..7]  (ds_read_b128 from Xb)
// B-frag: lane l -> col (l&15), same k pattern        (ds_read_b128 from Wt, transposed)
// C/D   : lane l -> col (l&15), rows 4*(l>>4)+reg     (HW-verified mapping)
// BN stats -> 32-way banked global atomics (bank = blockIdx & 31).

// ---------------- Layer 0: gather(67) @ w0(67x64), K padded to 96, stride 104 ----------------
__global__ __launch_bounds__(256) void layer0_kernel(
        const float* __restrict__ xyz, const float* __restrict__ points,
        const float* __restrict__ nxyz, const int* __restrict__ idxbuf,
        const unsigned short* __restrict__ wt0, unsigned short* __restrict__ z0,
        float* __restrict__ stats0) {
    __shared__ __attribute__((aligned(16))) unsigned short Xb[64*104];
    __shared__ __attribute__((aligned(16))) unsigned short Wt[64*104];
    __shared__ float ssum[64], ssq[64];
    const int tid = threadIdx.x;
    const int R = blockIdx.x * 64;
    const int bank = blockIdx.x & 31;
    if (tid < 64) { ssum[tid] = 0.f; ssq[tid] = 0.f; }
    {
        const uint4* src = (const uint4*)wt0;
        uint4* dst = (uint4*)Wt;
        for (int i = tid; i < 64*104/8; i += 256) dst[i] = src[i];
    }
    {
        int r = tid >> 2, q = tid & 3;
        int row = R + r;
        int gi = idxbuf[row];
        int b = row >> 15, s = (row >> 5) & 1023;
        const float4* pb4 = (const float4*)(points + (size_t)(b*8192 + gi) * 64);
        float4 f0 = pb4[q*4+0], f1 = pb4[q*4+1], f2 = pb4[q*4+2], f3 = pb4[q*4+3];
        unsigned short* xr = &Xb[r*104 + 3 + q*16];
        xr[0]  = (unsigned short)f2bf(f0.x); xr[1]  = (unsigned short)f2bf(f0.y);
        xr[2]  = (unsigned short)f2bf(f0.z); xr[3]  = (unsigned short)f2bf(f0.w);
        xr[4]  = (unsigned short)f2bf(f1.x); xr[5]  = (unsigned short)f2bf(f1.y);
        xr[6]  = (unsigned short)f2bf(f1.z); xr[7]  = (unsigned short)f2bf(f1.w);
        xr[8]  = (unsigned short)f2bf(f2.x); xr[9]  = (unsigned short)f2bf(f2.y);
        xr[10] = (unsigned short)f2bf(f2.z); xr[11] = (unsigned short)f2bf(f2.w);
        xr[12] = (unsigned short)f2bf(f3.x); xr[13] = (unsigned short)f2bf(f3.y);
        xr[14] = (unsigned short)f2bf(f3.z); xr[15] = (unsigned short)f2bf(f3.w);
        if (q == 0) {
#pragma unroll
            for (int e = 0; e < 3; ++e) {
                float vv = xyz[(size_t)(b*8192+gi)*3 + e] - nxyz[(size_t)(b*1024+s)*3 + e];
                Xb[r*104 + e] = (unsigned short)f2bf(vv);
            }
        }
    }
    for (int i = tid; i < 29*64; i += 256) {
        int e = 67 + (i % 29), r = i / 29;
        Xb[r*104 + e] = 0;
    }
    __syncthreads();
    const int l = tid & 63, w = tid >> 6;
    const int rsub = l & 15, kq = l >> 4;
    f32x4 acc[4];
#pragma unroll
    for (int cb = 0; cb < 4; ++cb) acc[cb] = (f32x4){0.f, 0.f, 0.f, 0.f};
    const int abase = (w*16 + rsub)*104 + kq*8;
    const int bbase = rsub*104 + kq*8;
#pragma unroll
    for (int ks = 0; ks < 3; ++ks) {
        bf16x8 A = *(const bf16x8*)&Xb[abase + ks*32];
#pragma unroll
        for (int cb = 0; cb < 4; ++cb) {
            bf16x8 Bf = *(const bf16x8*)&Wt[bbase + cb*16*104 + ks*32];
            acc[cb] = __builtin_amdgcn_mfma_f32_16x16x32_bf16(A, Bf, acc[cb], 0, 0, 0);
        }
    }
    unsigned short* zrow = z0 + (size_t)(R + w*16 + kq*4) * 64;
#pragma unroll
    for (int cb = 0; cb < 4; ++cb) {
        int c = cb*16 + rsub;
        float a0 = acc[cb][0], a1 = acc[cb][1], a2 = acc[cb][2], a3 = acc[cb][3];
        atomicAdd(&ssum[c], a0 + a1 + a2 + a3);
        atomicAdd(&ssq[c], a0*a0 + a1*a1 + a2*a2 + a3*a3);
#pragma unroll
        for (int j = 0; j < 4; ++j) zrow[j*64 + c] = (unsigned short)f2bf(acc[cb][j]);
    }
    __syncthreads();
    if (tid < 64) {
        atomicAdd(&stats0[bank*128 + tid], ssum[tid]);
        atomicAdd(&stats0[bank*128 + 64 + tid], ssq[tid]);
    }
}

// ---------------- Layer 1: relu(bn0(z0)) @ w1(64x64), stride 72 ----------------
__global__ __launch_bounds__(256) void layer1_kernel(
        const unsigned short* __restrict__ z0,
        const float* __restrict__ gsc, const float* __restrict__ gsh,
        const unsigned short* __restrict__ wt1, unsigned short* __restrict__ z1,
        float* __restrict__ stats1) {
    __shared__ __attribute__((aligned(16))) unsigned short Xb[64*72];
    __shared__ __attribute__((aligned(16))) unsigned short Wt[64*72];
    __shared__ float scale[64], shift[64], ssum[64], ssq[64];
    const int tid = threadIdx.x;
    const int R = blockIdx.x * 64;
    const int bank = blockIdx.x & 31;
    if (tid < 64) {
        scale[tid] = gsc[tid]; shift[tid] = gsh[tid];
        ssum[tid] = 0.f; ssq[tid] = 0.f;
    }
    {
        const uint4* src = (const uint4*)wt1;
        uint4* dst = (uint4*)Wt;
        for (int i = tid; i < 64*72/8; i += 256) dst[i] = src[i];
    }
    __syncthreads();                           // scale/shift ready
    const uint4* zg = (const uint4*)(z0 + (size_t)R * 64);
#pragma unroll
    for (int cch = 0; cch < 2; ++cch) {
        int flat8 = tid*2 + cch;               // 8-elem chunk id, 0..511
        uint4 a = zg[flat8];
        int r = flat8 >> 3, e0 = (flat8 & 7) * 8;
        unsigned int uu[4] = {a.x, a.y, a.z, a.w};
        bf16x8 xv;
#pragma unroll
        for (int j = 0; j < 8; ++j) {
            unsigned int ub = (j & 1) ? (uu[j>>1] >> 16) : (uu[j>>1] & 0xffffu);
            float v = bf2f(ub);
            v = fmaxf(v * scale[e0+j] + shift[e0+j], 0.f);
            xv[j] = (short)f2bf(v);
        }
        *(bf16x8*)&Xb[r*72 + e0] = xv;
    }
    __syncthreads();
    const int l = tid & 63, w = tid >> 6;
    const int rsub = l & 15, kq = l >> 4;
    f32x4 acc[4];
#pragma unroll
    for (int cb = 0; cb < 4; ++cb) acc[cb] = (f32x4){0.f, 0.f, 0.f, 0.f};
    const int abase = (w*16 + rsub)*72 + kq*8;
    const int bbase = rsub*72 + kq*8;
#pragma unroll
    for (int ks = 0; ks < 2; ++ks) {
        bf16x8 A = *(const bf16x8*)&Xb[abase + ks*32];
#pragma unroll
        for (int cb = 0; cb < 4; ++cb) {
            bf16x8 Bf = *(const bf16x8*)&Wt[bbase + cb*16*72 + ks*32];
            acc[cb] = __builtin_amdgcn_mfma_f32_16x16x32_bf16(A, Bf, acc[cb], 0, 0, 0);
        }
    }
    unsigned short* zrow = z1 + (size_t)(R + w*16 + kq*4) * 64;
#pragma unroll
    for (int cb = 0; cb < 4; ++cb) {
        int c = cb*16 + rsub;
        float a0 = acc[cb][0], a1 = acc[cb][1], a2 = acc[cb][2], a3 = acc[cb][3];
        atomicAdd(&ssum[c], a0 + a1 + a2 + a3);
        atomicAdd(&ssq[c], a0*a0 + a1*a1 + a2*a2 + a3*a3);
#pragma unroll
        for (int j = 0; j < 4; ++j) zrow[j*64 + c] = (unsigned short)f2bf(acc[cb][j]);
    }
    __syncthreads();
    if (tid < 64) {
        atomicAdd(&stats1[bank*128 + tid], ssum[tid]);
        atomicAdd(&stats1[bank*128 + 64 + tid], ssq[tid]);
    }
}

// ------- Layer 2: relu(bn1(z1)) @ w2(64x128); per-(b,s) channel max + stats -------
__global__ __launch_bounds__(256) void layer2_kernel(
        const unsigned short* __restrict__ z1,
        const float* __restrict__ gsc, const float* __restrict__ gsh,
        const unsigned short* __restrict__ wt2, float* __restrict__ maxz2,
        float* __restrict__ stats2) {
    __shared__ __attribute__((aligned(16))) unsigned short Xb[64*72];
    __shared__ __attribute__((aligned(16))) unsigned short Wt[128*72];
    __shared__ float scale[64], shift[64];
    __shared__ float ssum[128], ssq[128];
    __shared__ float gmx[2][8][128];
    const int tid = threadIdx.x;
    const int R = blockIdx.x * 64;
    const int bank = blockIdx.x & 31;
    if (tid < 64) { scale[tid] = gsc[tid]; shift[tid] = gsh[tid]; }
    if (tid < 128) { ssum[tid] = 0.f; ssq[tid] = 0.f; }
    {
        const uint4* src = (const uint4*)wt2;
        uint4* dst = (uint4*)Wt;
        for (int i = tid; i < 128*72/8; i += 256) dst[i] = src[i];
    }
    __syncthreads();
    const uint4* zg = (const uint4*)(z1 + (size_t)R * 64);
#pragma unroll
    for (int cch = 0; cch < 2; ++cch) {
        int flat8 = tid*2 + cch;
        uint4 a = zg[flat8];
        int r = flat8 >> 3, e0 = (flat8 & 7) * 8;
        unsigned int uu[4] = {a.x, a.y, a.z, a.w};
        bf16x8 xv;
#pragma unroll
        for (int j = 0; j < 8; ++j) {
            unsigned int ub = (j & 1) ? (uu[j>>1] >> 16) : (uu[j>>1] & 0xffffu);
            float v = bf2f(ub);
            v = fmaxf(v * scale[e0+j] + shift[e0+j], 0.f);
            xv[j] = (short)f2bf(v);
        }
        *(bf16x8*)&Xb[r*72 + e0] = xv;
    }
    __syncthreads();
    const int l = tid & 63, w = tid >> 6;
    const int rsub = l & 15, kq = l >> 4;
    f32x4 acc[8];
#pragma unroll
    for (int cb = 0; cb < 8; ++cb) acc[cb] = (f32x4){0.f, 0.f, 0.f, 0.f};
    const int abase = (w*16 + rsub)*72 + kq*8;
    const int bbase = rsub*72 + kq*8;
#pragma unroll
    for (int ks = 0; ks < 2; ++ks) {
        bf16x8 A = *(const bf16x8*)&Xb[abase + ks*32];
#pragma unroll
        for (int cb = 0; cb < 8; ++cb) {
            bf16x8 Bf = *(const bf16x8*)&Wt[bbase + cb*16*72 + ks*32];
            acc[cb] = __builtin_amdgcn_mfma_f32_16x16x32_bf16(A, Bf, acc[cb], 0, 0, 0);
        }
    }
    const int g = w >> 1;                       // 32-row group within block
    const int contrib = (w & 1) * 4 + kq;       // 0..7
#pragma unroll
    for (int cb = 0; cb < 8; ++cb) {
        int c = cb*16 + rsub;
        float a0 = acc[cb][0], a1 = acc[cb][1], a2 = acc[cb][2], a3 = acc[cb][3];
        atomicAdd(&ssum[c], a0 + a1 + a2 + a3);
        atomicAdd(&ssq[c], a0*a0 + a1*a1 + a2*a2 + a3*a3);
        gmx[g][contrib][c] = fmaxf(fmaxf(a0, a1), fmaxf(a2, a3));
    }
    __syncthreads();
    {
        int gg = tid >> 7, c = tid & 127;
        float m = gmx[gg][0][c];
#pragma unroll
        for (int i = 1; i < 8; ++i) m = fmaxf(m, gmx[gg][i][c]);
        maxz2[(size_t)(blockIdx.x*2 + gg) * 128 + c] = m;
    }
    if (tid < 128) {
        atomicAdd(&stats2[bank*256 + tid], ssum[tid]);
        atomicAdd(&stats2[bank*256 + 128 + tid], ssq[tid]);
    }
}

// ---------------- Final: out = relu(scale2*maxz2 + shift2) ----------------
__global__ __launch_bounds__(256) void final_kernel(
        const float* __restrict__ maxz2,
        const float* __restrict__ sc, const float* __restrict__ sh,
        float* __restrict__ out) {
    const int i = blockIdx.x * 256 + threadIdx.x;    // over 8*1024*128
    const int f = i & 127;
    out[24576 + i] = fmaxf(maxz2[i]*sc[f] + sh[f], 0.f);
}

extern "C" void kernel_launch(void* const* d_in, const int* in_sizes, int n_in,
                              void* d_out, int out_size, void* d_ws, size_t ws_size,
                              hipStream_t stream) {
    const float* xyz    = (const float*)d_in[0];
    const float* points = (const float*)d_in[1];
    const float* w0     = (const float*)d_in[2];
    const float* g0     = (const float*)d_in[3];
    const float* b0     = (const float*)d_in[4];
    const float* w1     = (const float*)d_in[5];
    const float* g1     = (const float*)d_in[6];
    const float* b1     = (const float*)d_in[7];
    const float* w2     = (const float*)d_in[8];
    const float* g2     = (const float*)d_in[9];
    const float* b2     = (const float*)d_in[10];
    float* out = (float*)d_out;
    char* ws = (char*)d_ws;

    // workspace layout (bytes), all 256-aligned:
    float* nxyz            = (float*)(ws + 0);          // 24576 f32
    int*   idxbuf          = (int*)  (ws + 98304);      // 262144 i32
    unsigned short* z0     = (unsigned short*)(ws + 1148928);   // 32 MB bf16
    unsigned short* z1     = (unsigned short*)(ws + 34703360);  // 32 MB bf16
    float* maxz2           = (float*)(ws + 68257792);   // 4 MB f32
    unsigned short* wt0    = (unsigned short*)(ws + 72452096);  // 64*104 bf16
    unsigned short* wt1    = (unsigned short*)(ws + 72465408);  // 64*72 bf16
    unsigned short* wt2    = (unsigned short*)(ws + 72474624);  // 128*72 bf16
    float* statsB          = (float*)(ws + 72493056);   // 16384 f32 (banked stats, 64 KB)
    float* st0             = statsB;                    // 32 x 128
    float* st1             = statsB + 4096;             // 32 x 128
    float* st2             = statsB + 8192;             // 32 x 256
    float* scsh            = (float*)(ws + 72558592);   // 512 f32
    float* sc0 = scsh,        * sh0 = scsh + 64;
    float* sc1 = scsh + 128,  * sh1 = scsh + 192;
    float* sc2 = scsh + 256,  * sh2 = scsh + 384;

    hipMemsetAsync(statsB, 0, 16384 * sizeof(float), stream);
    prep_w<<<26, 256, 0, stream>>>(w0, w1, w2, wt0, wt1, wt2);
    fps_kernel<<<8, 256, 0, stream>>>(xyz, nxyz, out);
    ballquery_kernel<<<2048, 256, 0, stream>>>(xyz, nxyz, idxbuf);
    layer0_kernel<<<4096, 256, 0, stream>>>(xyz, points, nxyz, idxbuf, wt0, z0, st0);
    bnprep64<<<1, 64, 0, stream>>>(st0, g0, b0, sc0, sh0);
    layer1_kernel<<<4096, 256, 0, stream>>>(z0, sc0, sh0, wt1, z1, st1);
    bnprep64<<<1, 64, 0, stream>>>(st1, g1, b1, sc1, sh1);
    layer2_kernel<<<4096, 256, 0, stream>>>(z1, sc1, sh1, wt2, maxz2, st2);
    bnprep128<<<1, 128, 0, stream>>>(st2, g2, b2, sc2, sh2);
    final_kernel<<<4096, 256, 0, stream>>>(maxz2, sc2, sh2, out);
}